// Round 26
// baseline (787.130 us; speedup 1.0000x reference)
//
#include <hip/hip_runtime.h>
#include <math.h>

#define HWDIM 128
#define IMG   (HWDIM * HWDIM)       // 16384
#define PLANE (4 * 64 * IMG)        // elems of one [B,64,H,W] tensor

typedef __attribute__((ext_vector_type(8))) short bf16x8;
typedef __attribute__((ext_vector_type(4))) float f32x4;
typedef __attribute__((ext_vector_type(4))) int   i32x4;

__device__ __forceinline__ unsigned short f2bf(float f) {
    unsigned u = __builtin_bit_cast(unsigned, f);
    u += 0x7FFFu + ((u >> 16) & 1u);          // RNE
    return (unsigned short)(u >> 16);
}
__device__ __forceinline__ float bf2f(unsigned short h) {
    unsigned u = ((unsigned)h) << 16;
    return __builtin_bit_cast(float, u);
}
__device__ __forceinline__ float sigmoidf_(float x) {
    return 1.f / (1.f + __expf(-x));
}
__device__ __forceinline__ float tanhf_(float x) {
    return 1.f - 2.f / (__expf(2.f * x) + 1.f);
}

// ---- weight prep: W_cell[256][128][3][3] -> Wg2[9][256][128] bf16
//                   W_seq [64][64][3][3]   -> Ws2[9][64][64]   bf16
__global__ void prep_weights_kernel(const float* __restrict__ Wc,
                                    const float* __restrict__ Ws,
                                    unsigned short* __restrict__ Wg2,
                                    unsigned short* __restrict__ Ws2) {
    int i = blockIdx.x * 256 + threadIdx.x;
    if (i < 9 * 256 * 128) {
        int tap = i >> 15, r = i & 32767, co = r >> 7, ci = r & 127;
        Wg2[i] = f2bf(Wc[(co * 128 + ci) * 9 + tap]);
    }
    if (i < 9 * 64 * 64) {
        int tap = i / 4096, r = i & 4095, co = r >> 6, ci = r & 63;
        Ws2[i] = f2bf(Ws[(co * 64 + ci) * 9 + tap]);
    }
}

// ---- seq conv, ALL 8 timesteps: 2-ROW blocks (R18-proven, 108 us). UNCHANGED.
__global__ __launch_bounds__(512, 4) void seq_conv_all(
    const float* __restrict__ xinp,           // [8][4][64][128][128]
    const unsigned short* __restrict__ Ws2,   // [9][64][64]
    const float* __restrict__ bseq,           // [64]
    float* __restrict__ xout)                 // [8][4][64][128][128]
{
    __shared__ __align__(16) unsigned short tile[4 * 130 * 76];   // 79040 B

    const int tid = threadIdx.x;
    const int sub = blockIdx.x;
    const int bid = (sub & 7) * 256 + (sub >> 3);   // XCD swizzle (2048%8==0)
    const int t  = bid >> 8;
    const int b  = (bid >> 6) & 3;
    const int yp = bid & 63;
    const int y0 = yp * 2;

    const float* xb = xinp + (size_t)t * PLANE + (size_t)b * 64 * IMG;

    float4 ga[8], gb[8];
    #pragma unroll
    for (int it = 0; it < 8; ++it) {
        int i = tid + it * 512;                 // i < 4096
        int xq = i & 31, cip = (i >> 5) & 31, ry = i >> 10;
        int gy = y0 - 1 + ry;
        int ci = cip * 2;
        float4 va = {0.f, 0.f, 0.f, 0.f}, vb = {0.f, 0.f, 0.f, 0.f};
        if ((unsigned)gy < 128u) {
            va = *(const float4*)(xb + (size_t)ci * IMG + gy * HWDIM + xq * 4);
            vb = *(const float4*)(xb + (size_t)(ci + 1) * IMG + gy * HWDIM + xq * 4);
        }
        ga[it] = va; gb[it] = vb;
    }
    #pragma unroll
    for (int it = 0; it < 8; ++it) {
        int i = tid + it * 512;
        int xq = i & 31, cip = (i >> 5) & 31, ry = i >> 10;
        int ci = cip * 2;
        const float* pa = (const float*)&ga[it];
        const float* pb = (const float*)&gb[it];
        #pragma unroll
        for (int j = 0; j < 4; ++j) {
            unsigned pk = (unsigned)f2bf(pa[j]) | ((unsigned)f2bf(pb[j]) << 16);
            *(unsigned*)(tile + (ry * 130 + 1 + xq * 4 + j) * 76 + ci) = pk;
        }
    }
    if (tid < 256) {        // halo columns = image border -> zero (4 rows)
        int e = tid & 1, cip = (tid >> 1) & 31, ry = tid >> 6;
        int xt = e ? 129 : 0;
        *(unsigned*)(tile + (ry * 130 + xt) * 76 + cip * 2) = 0u;
    }
    __syncthreads();

    const int lane = tid & 63;
    const int wv = tid >> 6;
    const int w  = wv & 3;          // cout stripe w*16
    const int rh = wv >> 2;         // output row (0/1)
    const int ln = lane & 15, lg = lane >> 4;

    f32x4 acc[8];
    #pragma unroll
    for (int n = 0; n < 8; ++n) acc[n] = (f32x4){0.f, 0.f, 0.f, 0.f};

    const unsigned short* wbase = Ws2 + (size_t)(w * 16 + ln) * 64 + lg * 8;
    auto WL = [&](int step) -> bf16x8 {
        int tap = step >> 1, kk = step & 1;
        return *(const bf16x8*)(wbase + tap * 4096 + kk * 32);
    };
    auto MS = [&](bf16x8 wf, int step) {
        int tap = step >> 1, kk = step & 1;
        int dy = tap / 3, dxx = tap % 3;
        #pragma unroll
        for (int n = 0; n < 8; ++n) {
            bf16x8 imf = *(const bf16x8*)(tile + ((rh + dy) * 130 + n * 16 + ln + dxx) * 76 + kk * 32 + lg * 8);
            acc[n] = __builtin_amdgcn_mfma_f32_16x16x32_bf16(wf, imf, acc[n], 0, 0, 0);
        }
    };
    bf16x8 wA = WL(0), wB;
    #pragma unroll
    for (int st = 0; st < 18; st += 2) {
        wB = WL(st + 1);
        MS(wA, st);
        if (st + 2 < 18) wA = WL(st + 2);
        MS(wB, st + 1);
    }

    float* xout_t = xout + (size_t)t * PLANE;
    const int co = w * 16 + lg * 4;
    const int gy = y0 + rh;
    #pragma unroll
    for (int r = 0; r < 4; ++r) {
        const float bv = bseq[co + r];
        float* dst = xout_t + ((size_t)b * 64 + co + r) * IMG + (size_t)gy * HWDIM;
        #pragma unroll
        for (int n = 0; n < 8; ++n)
            dst[n * 16 + ln] = acc[n][r] + bv;
    }
}

// ---- gates conv + LSTM, WEIGHTS-RESIDENT: block = 4 rows x 64 px x 64 co.
// Per kh-half the full 9-tap x 64co x 64ci weight slab sits in LDS
// (wlds[9][64][72] = 82.9 KB) -> the 9-tap inner loops run with ZERO
// barriers; only 8 barriers per block total (vs 36). Grid 1024; 1 block/CU.
__global__ __launch_bounds__(512, 1) void gates_lstm_mfma(
    const float* __restrict__ xo,             // xout_t [4][64][128][128] fp32
    const unsigned short* __restrict__ hin,   // [4][128][128][64] bf16
    const unsigned short* __restrict__ Wg2,   // [9][256][128]
    const float* __restrict__ bcell,          // [256]
    unsigned short* __restrict__ hout,        // [4][128][128][64] bf16
    unsigned short* __restrict__ cbuf,        // [4][128][128][64] bf16 in/out
    float* __restrict__ h32)                  // h_final fp32 CHW (t=7) or null
{
    __shared__ __align__(16) unsigned short wlds[9][64][72];    // 82944 B
    __shared__ __align__(16) unsigned short btile[6][66][36];   // 28512 B

    const int tid = threadIdx.x;
    const int sub = blockIdx.x;
    const int bid = (sub & 7) * 128 + (sub >> 3);  // XCD swizzle (1024%8==0)
    const int b  = bid >> 8;
    const int yq = (bid >> 3) & 31;
    const int xh = (bid >> 2) & 1;
    const int cg = bid & 3;         // ch quarter (ch base cg*16)
    const int y0 = yq * 4;
    const int x0 = xh * 64;

    const int lane = tid & 63;
    const int wv = tid >> 6;
    const int rh = wv >> 1;         // output row 0..3
    const int nh = wv & 1;          // px half (32 px)
    const int ln = lane & 15, lg = lane >> 4;

    const size_t pixb = (size_t)b * 128 * 128;
    const float* xb = xo + (size_t)b * 64 * IMG;

    // ---- weight staging: 9 chunks/thread (one per tap); kh = ci half ----
    const int wsl  = tid & 7;           // 16B chunk within 64-ci row
    const int wlco = tid >> 3;          // 0..63 local co
    const int wgco = (wlco >> 4) * 64 + cg * 16 + (wlco & 15);
    const unsigned short* wsrc = Wg2 + (size_t)wgco * 128 + wsl * 8;

    i32x4 wreg[9];
    auto LOADW = [&](int kh) {
        #pragma unroll
        for (int tp = 0; tp < 9; ++tp)
            wreg[tp] = *(const i32x4*)(wsrc + (size_t)tp * 32768 + kh * 64);
    };
    auto WRITEW = [&]() {
        #pragma unroll
        for (int tp = 0; tp < 9; ++tp)
            *(i32x4*)(&wlds[tp][wlco][wsl * 8]) = wreg[tp];
    };

    // ---- B staging (R24-proven): 32-ci slices kk 0..3 ----
    float4 xa[3], xc[3];
    float  ea, eb;
    i32x4 bv[4];

    auto LOADB = [&](int kk) {
        if (kk < 2) {
            #pragma unroll
            for (int it = 0; it < 3; ++it) {
                int i = tid + it * 512;               // i < 1536
                int xq = i & 15, cip = (i >> 4) & 15, ry = i >> 8;
                int gy = y0 - 1 + ry;
                int ci = kk * 32 + cip * 2;
                float4 va = {0.f, 0.f, 0.f, 0.f}, vb = {0.f, 0.f, 0.f, 0.f};
                if ((unsigned)gy < 128u) {
                    va = *(const float4*)(xb + (size_t)ci * IMG + gy * HWDIM + x0 + xq * 4);
                    vb = *(const float4*)(xb + (size_t)(ci + 1) * IMG + gy * HWDIM + x0 + xq * 4);
                }
                xa[it] = va; xc[it] = vb;
            }
            ea = 0.f; eb = 0.f;
            {
                int e = tid & 1, cip = (tid >> 1) & 15, ry = tid >> 5;
                int gx = x0 - 1 + (e ? 65 : 0);
                int gy = y0 - 1 + ry;
                int ci = kk * 32 + cip * 2;
                if (tid < 192 && (unsigned)gy < 128u && (unsigned)gx < 128u) {
                    ea = xb[(size_t)ci * IMG + gy * HWDIM + gx];
                    eb = xb[(size_t)(ci + 1) * IMG + gy * HWDIM + gx];
                }
            }
        } else {
            const unsigned short* src = hin + pixb * 64 + (kk & 1) * 32;
            #pragma unroll
            for (int it = 0; it < 4; ++it) {
                int i = tid + it * 512;
                i32x4 v = {0, 0, 0, 0};
                if (i < 1584) {
                    int g4 = i & 3, rem = i >> 2;       // rem < 396
                    int pxt = rem % 66, ry = rem / 66;
                    int gy = y0 - 1 + ry, gxx = x0 - 1 + pxt;
                    if ((unsigned)gy < 128u && (unsigned)gxx < 128u)
                        v = *(const i32x4*)(src + ((size_t)gy * 128 + gxx) * 64 + g4 * 8);
                }
                bv[it] = v;
            }
        }
    };
    auto WRITEB = [&](int kk) {
        if (kk < 2) {
            #pragma unroll
            for (int it = 0; it < 3; ++it) {
                int i = tid + it * 512;
                int xq = i & 15, cip = (i >> 4) & 15, ry = i >> 8;
                const float* pa = (const float*)&xa[it];
                const float* pb = (const float*)&xc[it];
                #pragma unroll
                for (int j = 0; j < 4; ++j) {
                    unsigned pk = (unsigned)f2bf(pa[j]) | ((unsigned)f2bf(pb[j]) << 16);
                    *(unsigned*)(&btile[ry][1 + xq * 4 + j][cip * 2]) = pk;
                }
            }
            if (tid < 192) {
                int e = tid & 1, cip = (tid >> 1) & 15, ry = tid >> 5;
                unsigned pk = (unsigned)f2bf(ea) | ((unsigned)f2bf(eb) << 16);
                *(unsigned*)(&btile[ry][e ? 65 : 0][cip * 2]) = pk;
            }
        } else {
            #pragma unroll
            for (int it = 0; it < 4; ++it) {
                int i = tid + it * 512;
                if (i < 1584) {
                    int g4 = i & 3, rem = i >> 2;
                    int pxt = rem % 66, ry = rem / 66;
                    *(i32x4*)(&btile[ry][pxt][g4 * 8]) = bv[it];
                }
            }
        }
    };

    // ---- prologue: weights half 0 + btile slice 0 ----
    LOADW(0);
    LOADB(0);
    WRITEW();
    WRITEB(0);
    __syncthreads();

    f32x4 acc[4][2];                // [gate][n-frag] (32 px per wave)
    #pragma unroll
    for (int g = 0; g < 4; ++g)
        #pragma unroll
        for (int n = 0; n < 2; ++n) acc[g][n] = (f32x4){0.f, 0.f, 0.f, 0.f};

    auto NINETAPS = [&](int k2) {
        #pragma unroll
        for (int tap = 0; tap < 9; ++tap) {
            const int dy = tap / 3, dxx = tap % 3;
            bf16x8 wf[4];
            #pragma unroll
            for (int g = 0; g < 4; ++g)
                wf[g] = *(const bf16x8*)(&wlds[tap][g * 16 + ln][k2 * 32 + lg * 8]);
            #pragma unroll
            for (int n = 0; n < 2; ++n) {
                bf16x8 af = *(const bf16x8*)(&btile[rh + dy][nh * 32 + n * 16 + ln + dxx][lg * 8]);
                #pragma unroll
                for (int g = 0; g < 4; ++g)
                    acc[g][n] = __builtin_amdgcn_mfma_f32_16x16x32_bf16(af, wf[g], acc[g][n], 0, 0, 0);
            }
        }
    };

    // phase 0: ci 0..31 (x), barrier-free 9-tap loop
    LOADB(1);
    NINETAPS(0);
    __syncthreads();
    WRITEB(1);
    __syncthreads();

    // phase 1: ci 32..63 (x); prefetch weight half 1 + h slice during compute
    LOADW(1);
    LOADB(2);
    NINETAPS(1);
    __syncthreads();
    WRITEW();
    WRITEB(2);
    __syncthreads();

    // phase 2: ci 64..95 (h)
    LOADB(3);
    NINETAPS(0);
    __syncthreads();
    WRITEB(3);
    __syncthreads();

    // phase 3: ci 96..127 (h)
    NINETAPS(1);

    // ---- in-register LSTM pointwise: lane owns ch, all 4 gates in acc ----
    const int ch = cg * 16 + ln;                // 0..63
    const int gy = y0 + rh;
    const float bi = bcell[ch], bf_ = bcell[64 + ch];
    const float bg = bcell[128 + ch], bo = bcell[192 + ch];

    #pragma unroll
    for (int n = 0; n < 2; ++n) {
        #pragma unroll
        for (int r = 0; r < 4; ++r) {
            const int col = x0 + nh * 32 + n * 16 + lg * 4 + r;
            float gi = acc[0][n][r] + bi;
            float gf = acc[1][n][r] + bf_;
            float gg = acc[2][n][r] + bg;
            float go = acc[3][n][r] + bo;
            float si = sigmoidf_(gi);
            float sf = sigmoidf_(gf);
            float tg = tanhf_(gg);
            float so = sigmoidf_(go);
            const size_t pixbase = pixb + (size_t)gy * 128 + col;
            const size_t cidx = pixbase * 64 + ch;
            float cold = bf2f(cbuf[cidx]);
            float cn = sf * cold + si * tg;
            cbuf[cidx] = f2bf(cn);
            float hv = so * tanhf_(cn);
            hout[cidx] = f2bf(hv);
            if (h32) h32[((size_t)b * 64 + ch) * IMG + (size_t)gy * HWDIM + col] = hv;
        }
    }
}

extern "C" void kernel_launch(void* const* d_in, const int* in_sizes, int n_in,
                              void* d_out, int out_size, void* d_ws, size_t ws_size,
                              hipStream_t stream) {
    const float* xinp   = (const float*)d_in[0]; // [8,4,64,128,128]
    const float* W_seq  = (const float*)d_in[1];
    const float* b_seq  = (const float*)d_in[2];
    const float* W_cell = (const float*)d_in[3];
    const float* b_cell = (const float*)d_in[4];

    float* out     = (float*)d_out;
    float* h_final = out;                    // [4,64,128,128] fp32
    float* xout    = out + PLANE;            // [8,4,64,128,128] fp32

    // ws (bf16 elems): c | h0 | h1 | Wg2 | Ws2   (~25.8 MB)
    unsigned short* cbuf = (unsigned short*)d_ws;
    unsigned short* hb0  = cbuf + PLANE;
    unsigned short* hb1  = hb0 + PLANE;
    unsigned short* Wg2  = hb1 + PLANE;
    unsigned short* Ws2  = Wg2 + 9 * 256 * 128;
    unsigned short* hbufs[2] = { hb0, hb1 };

    hipMemsetAsync(hb0,  0, (size_t)PLANE * sizeof(unsigned short), stream); // h0
    hipMemsetAsync(cbuf, 0, (size_t)PLANE * sizeof(unsigned short), stream); // c0

    prep_weights_kernel<<<1152, 256, 0, stream>>>(W_cell, W_seq, Wg2, Ws2);

    // all 8 timesteps' seq convs up front; gates then run back-to-back
    // with warm-L2 weights.
    seq_conv_all<<<2048, 512, 0, stream>>>(xinp, Ws2, b_seq, xout);

    for (int t = 0; t < 8; ++t) {
        gates_lstm_mfma<<<1024, 512, 0, stream>>>(
            xout + (size_t)t * PLANE, hbufs[t & 1], Wg2, b_cell,
            hbufs[(t + 1) & 1], cbuf,
            (t == 7) ? h_final : (float*)nullptr);
    }
}

// Round 27
// 507.607 us; speedup vs baseline: 1.5507x; 1.5507x over previous
//
#include <hip/hip_runtime.h>
#include <math.h>

#define HWDIM 128
#define IMG   (HWDIM * HWDIM)       // 16384
#define PLANE (4 * 64 * IMG)        // elems of one [B,64,H,W] tensor

typedef __attribute__((ext_vector_type(8))) short bf16x8;
typedef __attribute__((ext_vector_type(4))) float f32x4;
typedef __attribute__((ext_vector_type(4))) int   i32x4;

__device__ __forceinline__ unsigned short f2bf(float f) {
    unsigned u = __builtin_bit_cast(unsigned, f);
    u += 0x7FFFu + ((u >> 16) & 1u);          // RNE
    return (unsigned short)(u >> 16);
}
__device__ __forceinline__ float bf2f(unsigned short h) {
    unsigned u = ((unsigned)h) << 16;
    return __builtin_bit_cast(float, u);
}
__device__ __forceinline__ float sigmoidf_(float x) {
    return 1.f / (1.f + __expf(-x));
}
__device__ __forceinline__ float tanhf_(float x) {
    return 1.f - 2.f / (__expf(2.f * x) + 1.f);
}

// ---- weight prep: W_cell[256][128][3][3] -> Wg2[9][256][128] bf16
//                   W_seq [64][64][3][3]   -> Ws2[9][64][64]   bf16
__global__ void prep_weights_kernel(const float* __restrict__ Wc,
                                    const float* __restrict__ Ws,
                                    unsigned short* __restrict__ Wg2,
                                    unsigned short* __restrict__ Ws2) {
    int i = blockIdx.x * 256 + threadIdx.x;
    if (i < 9 * 256 * 128) {
        int tap = i >> 15, r = i & 32767, co = r >> 7, ci = r & 127;
        Wg2[i] = f2bf(Wc[(co * 128 + ci) * 9 + tap]);
    }
    if (i < 9 * 64 * 64) {
        int tap = i / 4096, r = i & 4095, co = r >> 6, ci = r & 63;
        Ws2[i] = f2bf(Ws[(co * 64 + ci) * 9 + tap]);
    }
}

// ---- seq conv, ALL 8 timesteps: 2-ROW blocks (R18-proven, 108 us). UNCHANGED.
__global__ __launch_bounds__(512, 4) void seq_conv_all(
    const float* __restrict__ xinp,           // [8][4][64][128][128]
    const unsigned short* __restrict__ Ws2,   // [9][64][64]
    const float* __restrict__ bseq,           // [64]
    float* __restrict__ xout)                 // [8][4][64][128][128]
{
    __shared__ __align__(16) unsigned short tile[4 * 130 * 76];   // 79040 B

    const int tid = threadIdx.x;
    const int sub = blockIdx.x;
    const int bid = (sub & 7) * 256 + (sub >> 3);   // XCD swizzle (2048%8==0)
    const int t  = bid >> 8;
    const int b  = (bid >> 6) & 3;
    const int yp = bid & 63;
    const int y0 = yp * 2;

    const float* xb = xinp + (size_t)t * PLANE + (size_t)b * 64 * IMG;

    float4 ga[8], gb[8];
    #pragma unroll
    for (int it = 0; it < 8; ++it) {
        int i = tid + it * 512;                 // i < 4096
        int xq = i & 31, cip = (i >> 5) & 31, ry = i >> 10;
        int gy = y0 - 1 + ry;
        int ci = cip * 2;
        float4 va = {0.f, 0.f, 0.f, 0.f}, vb = {0.f, 0.f, 0.f, 0.f};
        if ((unsigned)gy < 128u) {
            va = *(const float4*)(xb + (size_t)ci * IMG + gy * HWDIM + xq * 4);
            vb = *(const float4*)(xb + (size_t)(ci + 1) * IMG + gy * HWDIM + xq * 4);
        }
        ga[it] = va; gb[it] = vb;
    }
    #pragma unroll
    for (int it = 0; it < 8; ++it) {
        int i = tid + it * 512;
        int xq = i & 31, cip = (i >> 5) & 31, ry = i >> 10;
        int ci = cip * 2;
        const float* pa = (const float*)&ga[it];
        const float* pb = (const float*)&gb[it];
        #pragma unroll
        for (int j = 0; j < 4; ++j) {
            unsigned pk = (unsigned)f2bf(pa[j]) | ((unsigned)f2bf(pb[j]) << 16);
            *(unsigned*)(tile + (ry * 130 + 1 + xq * 4 + j) * 76 + ci) = pk;
        }
    }
    if (tid < 256) {        // halo columns = image border -> zero (4 rows)
        int e = tid & 1, cip = (tid >> 1) & 31, ry = tid >> 6;
        int xt = e ? 129 : 0;
        *(unsigned*)(tile + (ry * 130 + xt) * 76 + cip * 2) = 0u;
    }
    __syncthreads();

    const int lane = tid & 63;
    const int wv = tid >> 6;
    const int w  = wv & 3;          // cout stripe w*16
    const int rh = wv >> 2;         // output row (0/1)
    const int ln = lane & 15, lg = lane >> 4;

    f32x4 acc[8];
    #pragma unroll
    for (int n = 0; n < 8; ++n) acc[n] = (f32x4){0.f, 0.f, 0.f, 0.f};

    const unsigned short* wbase = Ws2 + (size_t)(w * 16 + ln) * 64 + lg * 8;
    auto WL = [&](int step) -> bf16x8 {
        int tap = step >> 1, kk = step & 1;
        return *(const bf16x8*)(wbase + tap * 4096 + kk * 32);
    };
    auto MS = [&](bf16x8 wf, int step) {
        int tap = step >> 1, kk = step & 1;
        int dy = tap / 3, dxx = tap % 3;
        #pragma unroll
        for (int n = 0; n < 8; ++n) {
            bf16x8 imf = *(const bf16x8*)(tile + ((rh + dy) * 130 + n * 16 + ln + dxx) * 76 + kk * 32 + lg * 8);
            acc[n] = __builtin_amdgcn_mfma_f32_16x16x32_bf16(wf, imf, acc[n], 0, 0, 0);
        }
    };
    bf16x8 wA = WL(0), wB;
    #pragma unroll
    for (int st = 0; st < 18; st += 2) {
        wB = WL(st + 1);
        MS(wA, st);
        if (st + 2 < 18) wA = WL(st + 2);
        MS(wB, st + 1);
    }

    float* xout_t = xout + (size_t)t * PLANE;
    const int co = w * 16 + lg * 4;
    const int gy = y0 + rh;
    #pragma unroll
    for (int r = 0; r < 4; ++r) {
        const float bv = bseq[co + r];
        float* dst = xout_t + ((size_t)b * 64 + co + r) * IMG + (size_t)gy * HWDIM;
        #pragma unroll
        for (int n = 0; n < 8; ++n)
            dst[n * 16 + ln] = acc[n][r] + bv;
    }
}

// ---- gates conv + LSTM (R23-proven, ~47.5 us/dispatch): 36-stage loop,
// dbuf wlds, block = 4 rows x 64 px x 128 co; grid 512; LDS 49.0 KB.
__global__ __launch_bounds__(512, 4) void gates_lstm_mfma(
    const float* __restrict__ xo,             // xout_t [4][64][128][128] fp32
    const unsigned short* __restrict__ hin,   // [4][128][128][64] bf16
    const unsigned short* __restrict__ Wg2,   // [9][256][128]
    const float* __restrict__ bcell,          // [256]
    unsigned short* __restrict__ hout,        // [4][128][128][64] bf16
    unsigned short* __restrict__ cbuf,        // [4][128][128][64] bf16 in/out
    float* __restrict__ h32)                  // h_final fp32 CHW (t=7) or null
{
    __shared__ __align__(16) unsigned short wlds[2][128][40];   // 20480 B
    __shared__ __align__(16) unsigned short btile[6][66][36];   // 28512 B

    const int tid = threadIdx.x;
    const int sub = blockIdx.x;
    const int bid = (sub & 7) * 64 + (sub >> 3);   // XCD swizzle (512%8==0)
    const int b  = bid >> 7;
    const int yq = (bid >> 2) & 31;
    const int xh = (bid >> 1) & 1;
    const int cg = bid & 1;         // co group (ch base cg*32)
    const int y0 = yq * 4;
    const int x0 = xh * 64;

    const int lane = tid & 63;
    const int wv = tid >> 6;
    const int wm = wv & 1;          // ch stripe (16 within 32)
    const int rh = wv >> 1;         // output row 0..3
    const int ln = lane & 15, lg = lane >> 4;

    const size_t pixb = (size_t)b * 128 * 128;
    const float* xb = xo + (size_t)b * 64 * IMG;

    // ---- A staging: 1 x 16B chunk/thread; 128 co x 32 ci per stage ----
    const int lco = tid >> 2;           // 0..127
    const int sl  = tid & 3;
    const int gco = (lco >> 5) * 64 + cg * 32 + (lco & 31);
    const unsigned short* wsrcb = Wg2 + (size_t)gco * 128 + sl * 8;

    i32x4 av;
    float4 xa[3], xc[3];            // x-part main staging (kk 0/1)
    float  ea, eb;                  // x-part edge staging
    i32x4 bv[4];                    // h-part staging (kk 2/3)

    auto LOADA = [&](int tap, int kk) {
        av = *(const i32x4*)(wsrcb + (size_t)tap * 32768 + kk * 32);
    };
    auto WRITEA = [&](int buf) {
        *(i32x4*)(&wlds[buf][lco][sl * 8]) = av;
    };
    auto LOADB = [&](int kk) {
        if (kk < 2) {
            // main: [6 rows][64 px][32 ci]; i = (ry*16 + cip)*16 + xq; 1536 total
            #pragma unroll
            for (int it = 0; it < 3; ++it) {
                int i = tid + it * 512;               // i < 1536
                int xq = i & 15, cip = (i >> 4) & 15, ry = i >> 8;
                int gy = y0 - 1 + ry;
                int ci = kk * 32 + cip * 2;
                float4 va = {0.f, 0.f, 0.f, 0.f}, vb = {0.f, 0.f, 0.f, 0.f};
                if ((unsigned)gy < 128u) {
                    va = *(const float4*)(xb + (size_t)ci * IMG + gy * HWDIM + x0 + xq * 4);
                    vb = *(const float4*)(xb + (size_t)(ci + 1) * IMG + gy * HWDIM + x0 + xq * 4);
                }
                xa[it] = va; xc[it] = vb;
            }
            // edges: xt 0 (gx=x0-1) / 65 (gx=x0+64); 6 rows x 2 x 16 cip = 192
            ea = 0.f; eb = 0.f;
            {
                int e = tid & 1, cip = (tid >> 1) & 15, ry = tid >> 5;
                int gx = x0 - 1 + (e ? 65 : 0);
                int gy = y0 - 1 + ry;
                int ci = kk * 32 + cip * 2;
                if (tid < 192 && (unsigned)gy < 128u && (unsigned)gx < 128u) {
                    ea = xb[(size_t)ci * IMG + gy * HWDIM + gx];
                    eb = xb[(size_t)(ci + 1) * IMG + gy * HWDIM + gx];
                }
            }
        } else {
            // h-part: [6 rows][66 px][4 chunks]; i = (ry*66 + pxt)*4 + g4; 1584 total
            const unsigned short* src = hin + pixb * 64 + (kk & 1) * 32;
            #pragma unroll
            for (int it = 0; it < 4; ++it) {
                int i = tid + it * 512;
                i32x4 v = {0, 0, 0, 0};
                if (i < 1584) {
                    int g4 = i & 3, rem = i >> 2;       // rem < 396
                    int pxt = rem % 66, ry = rem / 66;
                    int gy = y0 - 1 + ry, gxx = x0 - 1 + pxt;
                    if ((unsigned)gy < 128u && (unsigned)gxx < 128u)
                        v = *(const i32x4*)(src + ((size_t)gy * 128 + gxx) * 64 + g4 * 8);
                }
                bv[it] = v;
            }
        }
    };
    auto WRITEB = [&](int kk) {
        if (kk < 2) {
            #pragma unroll
            for (int it = 0; it < 3; ++it) {
                int i = tid + it * 512;
                int xq = i & 15, cip = (i >> 4) & 15, ry = i >> 8;
                const float* pa = (const float*)&xa[it];
                const float* pb = (const float*)&xc[it];
                #pragma unroll
                for (int j = 0; j < 4; ++j) {
                    unsigned pk = (unsigned)f2bf(pa[j]) | ((unsigned)f2bf(pb[j]) << 16);
                    *(unsigned*)(&btile[ry][1 + xq * 4 + j][cip * 2]) = pk;
                }
            }
            if (tid < 192) {
                int e = tid & 1, cip = (tid >> 1) & 15, ry = tid >> 5;
                unsigned pk = (unsigned)f2bf(ea) | ((unsigned)f2bf(eb) << 16);
                *(unsigned*)(&btile[ry][e ? 65 : 0][cip * 2]) = pk;
            }
        } else {
            #pragma unroll
            for (int it = 0; it < 4; ++it) {
                int i = tid + it * 512;
                if (i < 1584) {
                    int g4 = i & 3, rem = i >> 2;
                    int pxt = rem % 66, ry = rem / 66;
                    *(i32x4*)(&btile[ry][pxt][g4 * 8]) = bv[it];
                }
            }
        }
    };

    LOADA(0, 0);
    LOADB(0);
    WRITEA(0);
    WRITEB(0);
    __syncthreads();

    f32x4 acc[4][4];                // [gate][n-frag]
    #pragma unroll
    for (int g = 0; g < 4; ++g)
        #pragma unroll
        for (int n = 0; n < 4; ++n) acc[g][n] = (f32x4){0.f, 0.f, 0.f, 0.f};

    for (int kk = 0; kk < 4; ++kk) {
        for (int tap = 0; tap < 9; ++tap) {
            const int s = kk * 9 + tap;
            const int buf = s & 1;
            if (s < 35) {
                const int ntap = (tap == 8) ? 0 : tap + 1;
                const int nkk  = (tap == 8) ? kk + 1 : kk;
                LOADA(ntap, nkk);
            }
            if (tap == 8 && kk < 3) LOADB(kk + 1);

            const int dy = tap / 3, dxx = tap % 3;
            bf16x8 wf[4];
            #pragma unroll
            for (int g = 0; g < 4; ++g)
                wf[g] = *(const bf16x8*)(&wlds[buf][g * 32 + wm * 16 + ln][lg * 8]);
            #pragma unroll
            for (int n = 0; n < 4; ++n) {
                bf16x8 af = *(const bf16x8*)(&btile[rh + dy][n * 16 + ln + dxx][lg * 8]);
                #pragma unroll
                for (int g = 0; g < 4; ++g)
                    acc[g][n] = __builtin_amdgcn_mfma_f32_16x16x32_bf16(af, wf[g], acc[g][n], 0, 0, 0);
            }

            if (s < 35) WRITEA((s + 1) & 1);
            if (tap == 8 && kk < 3) {
                __syncthreads();    // all waves done reading btile
                WRITEB(kk + 1);
            }
            if (s < 35) __syncthreads();
        }
    }

    // ---- in-register LSTM pointwise: lane owns ch, all 4 gates in acc ----
    const int ch = cg * 32 + wm * 16 + ln;      // 0..63
    const int gy = y0 + rh;
    const float bi = bcell[ch], bf_ = bcell[64 + ch];
    const float bg = bcell[128 + ch], bo = bcell[192 + ch];

    #pragma unroll
    for (int n = 0; n < 4; ++n) {
        #pragma unroll
        for (int r = 0; r < 4; ++r) {
            const int col = x0 + n * 16 + lg * 4 + r;
            float gi = acc[0][n][r] + bi;
            float gf = acc[1][n][r] + bf_;
            float gg = acc[2][n][r] + bg;
            float go = acc[3][n][r] + bo;
            float si = sigmoidf_(gi);
            float sf = sigmoidf_(gf);
            float tg = tanhf_(gg);
            float so = sigmoidf_(go);
            const size_t pixbase = pixb + (size_t)gy * 128 + col;
            const size_t cidx = pixbase * 64 + ch;
            float cold = bf2f(cbuf[cidx]);
            float cn = sf * cold + si * tg;
            cbuf[cidx] = f2bf(cn);
            float hv = so * tanhf_(cn);
            hout[cidx] = f2bf(hv);
            if (h32) h32[((size_t)b * 64 + ch) * IMG + (size_t)gy * HWDIM + col] = hv;
        }
    }
}

extern "C" void kernel_launch(void* const* d_in, const int* in_sizes, int n_in,
                              void* d_out, int out_size, void* d_ws, size_t ws_size,
                              hipStream_t stream) {
    const float* xinp   = (const float*)d_in[0]; // [8,4,64,128,128]
    const float* W_seq  = (const float*)d_in[1];
    const float* b_seq  = (const float*)d_in[2];
    const float* W_cell = (const float*)d_in[3];
    const float* b_cell = (const float*)d_in[4];

    float* out     = (float*)d_out;
    float* h_final = out;                    // [4,64,128,128] fp32
    float* xout    = out + PLANE;            // [8,4,64,128,128] fp32

    // ws (bf16 elems): c | h0 | h1 | Wg2 | Ws2   (~25.8 MB)
    unsigned short* cbuf = (unsigned short*)d_ws;
    unsigned short* hb0  = cbuf + PLANE;
    unsigned short* hb1  = hb0 + PLANE;
    unsigned short* Wg2  = hb1 + PLANE;
    unsigned short* Ws2  = Wg2 + 9 * 256 * 128;
    unsigned short* hbufs[2] = { hb0, hb1 };

    hipMemsetAsync(hb0,  0, (size_t)PLANE * sizeof(unsigned short), stream); // h0
    hipMemsetAsync(cbuf, 0, (size_t)PLANE * sizeof(unsigned short), stream); // c0

    prep_weights_kernel<<<1152, 256, 0, stream>>>(W_cell, W_seq, Wg2, Ws2);

    // all 8 timesteps' seq convs up front; gates then run back-to-back
    // with warm-L2 weights.
    seq_conv_all<<<2048, 512, 0, stream>>>(xinp, Ws2, b_seq, xout);

    for (int t = 0; t < 8; ++t) {
        gates_lstm_mfma<<<512, 512, 0, stream>>>(
            xout + (size_t)t * PLANE, hbufs[t & 1], Wg2, b_cell,
            hbufs[(t + 1) & 1], cbuf,
            (t == 7) ? h_final : (float*)nullptr);
    }
}

// Round 29
// 505.543 us; speedup vs baseline: 1.5570x; 1.0041x over previous
//
#include <hip/hip_runtime.h>
#include <math.h>

#define HWDIM 128
#define IMG   (HWDIM * HWDIM)       // 16384
#define PLANE (4 * 64 * IMG)        // elems of one [B,64,H,W] tensor

typedef __attribute__((ext_vector_type(8))) short bf16x8;
typedef __attribute__((ext_vector_type(4))) float f32x4;
typedef __attribute__((ext_vector_type(4))) int   i32x4;

__device__ __forceinline__ unsigned short f2bf(float f) {
    unsigned u = __builtin_bit_cast(unsigned, f);
    u += 0x7FFFu + ((u >> 16) & 1u);          // RNE
    return (unsigned short)(u >> 16);
}
__device__ __forceinline__ float bf2f(unsigned short h) {
    unsigned u = ((unsigned)h) << 16;
    return __builtin_bit_cast(float, u);
}
__device__ __forceinline__ float sigmoidf_(float x) {
    return 1.f / (1.f + __expf(-x));
}
__device__ __forceinline__ float tanhf_(float x) {
    return 1.f - 2.f / (__expf(2.f * x) + 1.f);
}

// ---- weight prep: W_cell[256][128][3][3] -> Wg2[9][256][128] bf16
//                   W_seq [64][64][3][3]   -> Ws2[9][64][64]   bf16
__global__ void prep_weights_kernel(const float* __restrict__ Wc,
                                    const float* __restrict__ Ws,
                                    unsigned short* __restrict__ Wg2,
                                    unsigned short* __restrict__ Ws2) {
    int i = blockIdx.x * 256 + threadIdx.x;
    if (i < 9 * 256 * 128) {
        int tap = i >> 15, r = i & 32767, co = r >> 7, ci = r & 127;
        Wg2[i] = f2bf(Wc[(co * 128 + ci) * 9 + tap]);
    }
    if (i < 9 * 64 * 64) {
        int tap = i / 4096, r = i & 4095, co = r >> 6, ci = r & 63;
        Ws2[i] = f2bf(Ws[(co * 64 + ci) * 9 + tap]);
    }
}

// ---- seq conv, ALL 8 timesteps: 2-ROW blocks (R18-proven, 108 us). UNCHANGED.
__global__ __launch_bounds__(512, 4) void seq_conv_all(
    const float* __restrict__ xinp,           // [8][4][64][128][128]
    const unsigned short* __restrict__ Ws2,   // [9][64][64]
    const float* __restrict__ bseq,           // [64]
    float* __restrict__ xout)                 // [8][4][64][128][128]
{
    __shared__ __align__(16) unsigned short tile[4 * 130 * 76];   // 79040 B

    const int tid = threadIdx.x;
    const int sub = blockIdx.x;
    const int bid = (sub & 7) * 256 + (sub >> 3);   // XCD swizzle (2048%8==0)
    const int t  = bid >> 8;
    const int b  = (bid >> 6) & 3;
    const int yp = bid & 63;
    const int y0 = yp * 2;

    const float* xb = xinp + (size_t)t * PLANE + (size_t)b * 64 * IMG;

    float4 ga[8], gb[8];
    #pragma unroll
    for (int it = 0; it < 8; ++it) {
        int i = tid + it * 512;                 // i < 4096
        int xq = i & 31, cip = (i >> 5) & 31, ry = i >> 10;
        int gy = y0 - 1 + ry;
        int ci = cip * 2;
        float4 va = {0.f, 0.f, 0.f, 0.f}, vb = {0.f, 0.f, 0.f, 0.f};
        if ((unsigned)gy < 128u) {
            va = *(const float4*)(xb + (size_t)ci * IMG + gy * HWDIM + xq * 4);
            vb = *(const float4*)(xb + (size_t)(ci + 1) * IMG + gy * HWDIM + xq * 4);
        }
        ga[it] = va; gb[it] = vb;
    }
    #pragma unroll
    for (int it = 0; it < 8; ++it) {
        int i = tid + it * 512;
        int xq = i & 31, cip = (i >> 5) & 31, ry = i >> 10;
        int ci = cip * 2;
        const float* pa = (const float*)&ga[it];
        const float* pb = (const float*)&gb[it];
        #pragma unroll
        for (int j = 0; j < 4; ++j) {
            unsigned pk = (unsigned)f2bf(pa[j]) | ((unsigned)f2bf(pb[j]) << 16);
            *(unsigned*)(tile + (ry * 130 + 1 + xq * 4 + j) * 76 + ci) = pk;
        }
    }
    if (tid < 256) {        // halo columns = image border -> zero (4 rows)
        int e = tid & 1, cip = (tid >> 1) & 31, ry = tid >> 6;
        int xt = e ? 129 : 0;
        *(unsigned*)(tile + (ry * 130 + xt) * 76 + cip * 2) = 0u;
    }
    __syncthreads();

    const int lane = tid & 63;
    const int wv = tid >> 6;
    const int w  = wv & 3;          // cout stripe w*16
    const int rh = wv >> 2;         // output row (0/1)
    const int ln = lane & 15, lg = lane >> 4;

    f32x4 acc[8];
    #pragma unroll
    for (int n = 0; n < 8; ++n) acc[n] = (f32x4){0.f, 0.f, 0.f, 0.f};

    const unsigned short* wbase = Ws2 + (size_t)(w * 16 + ln) * 64 + lg * 8;
    auto WL = [&](int step) -> bf16x8 {
        int tap = step >> 1, kk = step & 1;
        return *(const bf16x8*)(wbase + tap * 4096 + kk * 32);
    };
    auto MS = [&](bf16x8 wf, int step) {
        int tap = step >> 1, kk = step & 1;
        int dy = tap / 3, dxx = tap % 3;
        #pragma unroll
        for (int n = 0; n < 8; ++n) {
            bf16x8 imf = *(const bf16x8*)(tile + ((rh + dy) * 130 + n * 16 + ln + dxx) * 76 + kk * 32 + lg * 8);
            acc[n] = __builtin_amdgcn_mfma_f32_16x16x32_bf16(wf, imf, acc[n], 0, 0, 0);
        }
    };
    bf16x8 wA = WL(0), wB;
    #pragma unroll
    for (int st = 0; st < 18; st += 2) {
        wB = WL(st + 1);
        MS(wA, st);
        if (st + 2 < 18) wA = WL(st + 2);
        MS(wB, st + 1);
    }

    float* xout_t = xout + (size_t)t * PLANE;
    const int co = w * 16 + lg * 4;
    const int gy = y0 + rh;
    #pragma unroll
    for (int r = 0; r < 4; ++r) {
        const float bv = bseq[co + r];
        float* dst = xout_t + ((size_t)b * 64 + co + r) * IMG + (size_t)gy * HWDIM;
        #pragma unroll
        for (int n = 0; n < 8; ++n)
            dst[n * 16 + ln] = acc[n][r] + bv;
    }
}

// ---- gates conv + LSTM (R23-proven, ~47.5 us/dispatch): 36-stage loop,
// dbuf wlds, block = 4 rows x 64 px x 128 co; grid 512; LDS 49.0 KB.
__global__ __launch_bounds__(512, 4) void gates_lstm_mfma(
    const float* __restrict__ xo,             // xout_t [4][64][128][128] fp32
    const unsigned short* __restrict__ hin,   // [4][128][128][64] bf16
    const unsigned short* __restrict__ Wg2,   // [9][256][128]
    const float* __restrict__ bcell,          // [256]
    unsigned short* __restrict__ hout,        // [4][128][128][64] bf16
    unsigned short* __restrict__ cbuf,        // [4][128][128][64] bf16 in/out
    float* __restrict__ h32)                  // h_final fp32 CHW (t=7) or null
{
    __shared__ __align__(16) unsigned short wlds[2][128][40];   // 20480 B
    __shared__ __align__(16) unsigned short btile[6][66][36];   // 28512 B

    const int tid = threadIdx.x;
    const int sub = blockIdx.x;
    const int bid = (sub & 7) * 64 + (sub >> 3);   // XCD swizzle (512%8==0)
    const int b  = bid >> 7;
    const int yq = (bid >> 2) & 31;
    const int xh = (bid >> 1) & 1;
    const int cg = bid & 1;         // co group (ch base cg*32)
    const int y0 = yq * 4;
    const int x0 = xh * 64;

    const int lane = tid & 63;
    const int wv = tid >> 6;
    const int wm = wv & 1;          // ch stripe (16 within 32)
    const int rh = wv >> 1;         // output row 0..3
    const int ln = lane & 15, lg = lane >> 4;

    const size_t pixb = (size_t)b * 128 * 128;
    const float* xb = xo + (size_t)b * 64 * IMG;

    // ---- A staging: 1 x 16B chunk/thread; 128 co x 32 ci per stage ----
    const int lco = tid >> 2;           // 0..127
    const int sl  = tid & 3;
    const int gco = (lco >> 5) * 64 + cg * 32 + (lco & 31);
    const unsigned short* wsrcb = Wg2 + (size_t)gco * 128 + sl * 8;

    i32x4 av;
    float4 xa[3], xc[3];            // x-part main staging (kk 0/1)
    float  ea, eb;                  // x-part edge staging
    i32x4 bv[4];                    // h-part staging (kk 2/3)

    auto LOADA = [&](int tap, int kk) {
        av = *(const i32x4*)(wsrcb + (size_t)tap * 32768 + kk * 32);
    };
    auto WRITEA = [&](int buf) {
        *(i32x4*)(&wlds[buf][lco][sl * 8]) = av;
    };
    auto LOADB = [&](int kk) {
        if (kk < 2) {
            // main: [6 rows][64 px][32 ci]; i = (ry*16 + cip)*16 + xq; 1536 total
            #pragma unroll
            for (int it = 0; it < 3; ++it) {
                int i = tid + it * 512;               // i < 1536
                int xq = i & 15, cip = (i >> 4) & 15, ry = i >> 8;
                int gy = y0 - 1 + ry;
                int ci = kk * 32 + cip * 2;
                float4 va = {0.f, 0.f, 0.f, 0.f}, vb = {0.f, 0.f, 0.f, 0.f};
                if ((unsigned)gy < 128u) {
                    va = *(const float4*)(xb + (size_t)ci * IMG + gy * HWDIM + x0 + xq * 4);
                    vb = *(const float4*)(xb + (size_t)(ci + 1) * IMG + gy * HWDIM + x0 + xq * 4);
                }
                xa[it] = va; xc[it] = vb;
            }
            // edges: xt 0 (gx=x0-1) / 65 (gx=x0+64); 6 rows x 2 x 16 cip = 192
            ea = 0.f; eb = 0.f;
            {
                int e = tid & 1, cip = (tid >> 1) & 15, ry = tid >> 5;
                int gx = x0 - 1 + (e ? 65 : 0);
                int gy = y0 - 1 + ry;
                int ci = kk * 32 + cip * 2;
                if (tid < 192 && (unsigned)gy < 128u && (unsigned)gx < 128u) {
                    ea = xb[(size_t)ci * IMG + gy * HWDIM + gx];
                    eb = xb[(size_t)(ci + 1) * IMG + gy * HWDIM + gx];
                }
            }
        } else {
            // h-part: [6 rows][66 px][4 chunks]; i = (ry*66 + pxt)*4 + g4; 1584 total
            const unsigned short* src = hin + pixb * 64 + (kk & 1) * 32;
            #pragma unroll
            for (int it = 0; it < 4; ++it) {
                int i = tid + it * 512;
                i32x4 v = {0, 0, 0, 0};
                if (i < 1584) {
                    int g4 = i & 3, rem = i >> 2;       // rem < 396
                    int pxt = rem % 66, ry = rem / 66;
                    int gy = y0 - 1 + ry, gxx = x0 - 1 + pxt;
                    if ((unsigned)gy < 128u && (unsigned)gxx < 128u)
                        v = *(const i32x4*)(src + ((size_t)gy * 128 + gxx) * 64 + g4 * 8);
                }
                bv[it] = v;
            }
        }
    };
    auto WRITEB = [&](int kk) {
        if (kk < 2) {
            #pragma unroll
            for (int it = 0; it < 3; ++it) {
                int i = tid + it * 512;
                int xq = i & 15, cip = (i >> 4) & 15, ry = i >> 8;
                const float* pa = (const float*)&xa[it];
                const float* pb = (const float*)&xc[it];
                #pragma unroll
                for (int j = 0; j < 4; ++j) {
                    unsigned pk = (unsigned)f2bf(pa[j]) | ((unsigned)f2bf(pb[j]) << 16);
                    *(unsigned*)(&btile[ry][1 + xq * 4 + j][cip * 2]) = pk;
                }
            }
            if (tid < 192) {
                int e = tid & 1, cip = (tid >> 1) & 15, ry = tid >> 5;
                unsigned pk = (unsigned)f2bf(ea) | ((unsigned)f2bf(eb) << 16);
                *(unsigned*)(&btile[ry][e ? 65 : 0][cip * 2]) = pk;
            }
        } else {
            #pragma unroll
            for (int it = 0; it < 4; ++it) {
                int i = tid + it * 512;
                if (i < 1584) {
                    int g4 = i & 3, rem = i >> 2;
                    int pxt = rem % 66, ry = rem / 66;
                    *(i32x4*)(&btile[ry][pxt][g4 * 8]) = bv[it];
                }
            }
        }
    };

    LOADA(0, 0);
    LOADB(0);
    WRITEA(0);
    WRITEB(0);
    __syncthreads();

    f32x4 acc[4][4];                // [gate][n-frag]
    #pragma unroll
    for (int g = 0; g < 4; ++g)
        #pragma unroll
        for (int n = 0; n < 4; ++n) acc[g][n] = (f32x4){0.f, 0.f, 0.f, 0.f};

    for (int kk = 0; kk < 4; ++kk) {
        for (int tap = 0; tap < 9; ++tap) {
            const int s = kk * 9 + tap;
            const int buf = s & 1;
            if (s < 35) {
                const int ntap = (tap == 8) ? 0 : tap + 1;
                const int nkk  = (tap == 8) ? kk + 1 : kk;
                LOADA(ntap, nkk);
            }
            if (tap == 8 && kk < 3) LOADB(kk + 1);

            const int dy = tap / 3, dxx = tap % 3;
            bf16x8 wf[4];
            #pragma unroll
            for (int g = 0; g < 4; ++g)
                wf[g] = *(const bf16x8*)(&wlds[buf][g * 32 + wm * 16 + ln][lg * 8]);
            #pragma unroll
            for (int n = 0; n < 4; ++n) {
                bf16x8 af = *(const bf16x8*)(&btile[rh + dy][n * 16 + ln + dxx][lg * 8]);
                #pragma unroll
                for (int g = 0; g < 4; ++g)
                    acc[g][n] = __builtin_amdgcn_mfma_f32_16x16x32_bf16(af, wf[g], acc[g][n], 0, 0, 0);
            }

            if (s < 35) WRITEA((s + 1) & 1);
            if (tap == 8 && kk < 3) {
                __syncthreads();    // all waves done reading btile
                WRITEB(kk + 1);
            }
            if (s < 35) __syncthreads();
        }
    }

    // ---- in-register LSTM pointwise: lane owns ch, all 4 gates in acc ----
    const int ch = cg * 32 + wm * 16 + ln;      // 0..63
    const int gy = y0 + rh;
    const float bi = bcell[ch], bf_ = bcell[64 + ch];
    const float bg = bcell[128 + ch], bo = bcell[192 + ch];

    #pragma unroll
    for (int n = 0; n < 4; ++n) {
        #pragma unroll
        for (int r = 0; r < 4; ++r) {
            const int col = x0 + n * 16 + lg * 4 + r;
            float gi = acc[0][n][r] + bi;
            float gf = acc[1][n][r] + bf_;
            float gg = acc[2][n][r] + bg;
            float go = acc[3][n][r] + bo;
            float si = sigmoidf_(gi);
            float sf = sigmoidf_(gf);
            float tg = tanhf_(gg);
            float so = sigmoidf_(go);
            const size_t pixbase = pixb + (size_t)gy * 128 + col;
            const size_t cidx = pixbase * 64 + ch;
            float cold = bf2f(cbuf[cidx]);
            float cn = sf * cold + si * tg;
            cbuf[cidx] = f2bf(cn);
            float hv = so * tanhf_(cn);
            hout[cidx] = f2bf(hv);
            if (h32) h32[((size_t)b * 64 + ch) * IMG + (size_t)gy * HWDIM + col] = hv;
        }
    }
}

extern "C" void kernel_launch(void* const* d_in, const int* in_sizes, int n_in,
                              void* d_out, int out_size, void* d_ws, size_t ws_size,
                              hipStream_t stream) {
    const float* xinp   = (const float*)d_in[0]; // [8,4,64,128,128]
    const float* W_seq  = (const float*)d_in[1];
    const float* b_seq  = (const float*)d_in[2];
    const float* W_cell = (const float*)d_in[3];
    const float* b_cell = (const float*)d_in[4];

    float* out     = (float*)d_out;
    float* h_final = out;                    // [4,64,128,128] fp32
    float* xout    = out + PLANE;            // [8,4,64,128,128] fp32

    // ws (bf16 elems): c | h0 | h1 | Wg2 | Ws2   (~25.8 MB)
    unsigned short* cbuf = (unsigned short*)d_ws;
    unsigned short* hb0  = cbuf + PLANE;
    unsigned short* hb1  = hb0 + PLANE;
    unsigned short* Wg2  = hb1 + PLANE;
    unsigned short* Ws2  = Wg2 + 9 * 256 * 128;
    unsigned short* hbufs[2] = { hb0, hb1 };

    hipMemsetAsync(hb0,  0, (size_t)PLANE * sizeof(unsigned short), stream); // h0
    hipMemsetAsync(cbuf, 0, (size_t)PLANE * sizeof(unsigned short), stream); // c0

    prep_weights_kernel<<<1152, 256, 0, stream>>>(W_cell, W_seq, Wg2, Ws2);

    // all 8 timesteps' seq convs up front; gates then run back-to-back
    // with warm-L2 weights.
    seq_conv_all<<<2048, 512, 0, stream>>>(xinp, Ws2, b_seq, xout);

    for (int t = 0; t < 8; ++t) {
        gates_lstm_mfma<<<512, 512, 0, stream>>>(
            xout + (size_t)t * PLANE, hbufs[t & 1], Wg2, b_cell,
            hbufs[(t + 1) & 1], cbuf,
            (t == 7) ? h_final : (float*)nullptr);
    }
}